// Round 5
// baseline (1157.317 us; speedup 1.0000x reference)
//
#include <hip/hip_runtime.h>
#include <hip/hip_cooperative_groups.h>
#include <math.h>

namespace cg = cooperative_groups;

#define DSZ   64
#define NVOX  (DSZ*DSZ*DSZ)
#define NSTEP 7
#define VPT   2                    // voxels per thread (fused path)
#define FGRID (NVOX/256/VPT)       // 512 blocks = 2 blocks/CU -> safe cooperative

__device__ __forceinline__ float rcp_f(float x)  { return __builtin_amdgcn_rcpf(x); }
__device__ __forceinline__ float rsq_f(float x)  { return __builtin_amdgcn_rsqf(x); }

// ---------- SE(3) exp: xi=(v,w) -> R(3x3 row-major), t(3) ----------
__device__ __forceinline__ void se3_exp_dev(const float xi[6], float R[9], float t[3]) {
    float vx = xi[0], vy = xi[1], vz = xi[2];
    float wx = xi[3], wy = xi[4], wz = xi[5];
    float t2 = wx*wx + wy*wy + wz*wz;
    float t2c = fmaxf(t2, 1e-20f);
    float it    = rsq_f(t2c);        // 1/theta
    float theta = t2c*it;            // theta
    float s = __sinf(theta), c = __cosf(theta);
    float it2 = it*it;
    float A = s*it;
    float B = (1.0f - c)*it2;
    float C = (theta - s)*it2*it;
    bool sm = t2 < 1e-6f;            // error in A/B/C is *theta^2 downstream
    A = sm ? 1.0f - t2*(1.0f/6.0f)            : A;
    B = sm ? 0.5f - t2*(1.0f/24.0f)           : B;
    C = sm ? (1.0f/6.0f) - t2*(1.0f/120.0f)   : C;

    float xx = wx*wx, yy = wy*wy, zz = wz*wz;
    float xy = wx*wy, xz = wx*wz, yz = wy*wz;
    R[0] = 1.0f - B*(yy+zz);
    R[1] = -A*wz + B*xy;
    R[2] =  A*wy + B*xz;
    R[3] =  A*wz + B*xy;
    R[4] = 1.0f - B*(xx+zz);
    R[5] = -A*wx + B*yz;
    R[6] = -A*wy + B*xz;
    R[7] =  A*wx + B*yz;
    R[8] = 1.0f - B*(xx+yy);
    float V0 = 1.0f - C*(yy+zz);
    float V1 = -B*wz + C*xy;
    float V2 =  B*wy + C*xz;
    float V3 =  B*wz + C*xy;
    float V4 = 1.0f - C*(xx+zz);
    float V5 = -B*wx + C*yz;
    float V6 = -B*wy + C*xz;
    float V7 =  B*wx + C*yz;
    float V8 = 1.0f - C*(xx+yy);
    t[0] = V0*vx + V1*vy + V2*vz;
    t[1] = V3*vx + V4*vy + V5*vz;
    t[2] = V6*vx + V7*vy + V8*vz;
}

// ---------- SE(3) log: R,t -> xi=(v,w); sin recovered from cos ----------
__device__ __forceinline__ void se3_log_dev(const float R[9], const float t[3], float out[6]) {
    float tr = R[0] + R[4] + R[8];
    float cs = (tr - 1.0f)*0.5f;
    cs = fminf(fmaxf(cs, -1.0f + 1e-6f), 1.0f - 1e-6f);
    float theta = acosf(cs);
    float t2 = theta*theta;
    float ss2 = 1.0f - cs*cs;          // sin^2
    float isn = rsq_f(ss2);            // 1/sin
    float fac = theta*isn;             // theta/sin
    float sn  = ss2*isn;               // sin
    float coef = (1.0f - 0.5f*sn*theta*rcp_f(1.0f - cs)) * rcp_f(t2);
    bool sm = theta < 1e-3f;
    fac  = sm ? 1.0f + t2*(1.0f/6.0f) : fac;
    coef = sm ? (1.0f/12.0f)          : coef;

    float wx = 0.5f*(R[7]-R[5])*fac;
    float wy = 0.5f*(R[2]-R[6])*fac;
    float wz = 0.5f*(R[3]-R[1])*fac;
    float xx = wx*wx, yy = wy*wy, zz = wz*wz;
    float xy = wx*wy, xz = wx*wz, yz = wy*wz;
    float V0 = 1.0f - coef*(yy+zz);
    float V1 =  0.5f*wz + coef*xy;
    float V2 = -0.5f*wy + coef*xz;
    float V3 = -0.5f*wz + coef*xy;
    float V4 = 1.0f - coef*(xx+zz);
    float V5 =  0.5f*wx + coef*yz;
    float V6 =  0.5f*wy + coef*xz;
    float V7 = -0.5f*wx + coef*yz;
    float V8 = 1.0f - coef*(xx+yy);
    out[0] = V0*t[0] + V1*t[1] + V2*t[2];
    out[1] = V3*t[0] + V4*t[1] + V5*t[2];
    out[2] = V6*t[0] + V7*t[1] + V8*t[2];
    out[3] = wx; out[4] = wy; out[5] = wz;
}

// ---------- shared per-voxel step body ----------
__device__ __forceinline__ void step_voxel(int n, const float xi_own[6],
                                           const float2* __restrict__ v2,
                                           float out6[6]) {
    float Rm[9], tm[3];
    se3_exp_dev(xi_own, Rm, tm);

    int k = n & 63, j = (n >> 6) & 63, i = n >> 12;
    const float inv63 = 1.0f/63.0f;
    float p0 = (float)(2*i - 63)*inv63;
    float p1 = (float)(2*j - 63)*inv63;
    float p2 = (float)(2*k - 63)*inv63;

    float nl0 = Rm[0]*p0 + Rm[1]*p1 + Rm[2]*p2 + tm[0];
    float nl1 = Rm[3]*p0 + Rm[4]*p1 + Rm[5]*p2 + tm[1];
    float nl2 = Rm[6]*p0 + Rm[7]*p1 + Rm[8]*p2 + tm[2];

    float gx = fminf(fmaxf((nl2 + 1.0f)*0.5f*63.0f, 0.0f), 63.0f);
    float gy = fminf(fmaxf((nl1 + 1.0f)*0.5f*63.0f, 0.0f), 63.0f);
    float gz = fminf(fmaxf((nl0 + 1.0f)*0.5f*63.0f, 0.0f), 63.0f);
    float x0f = floorf(gx), y0f = floorf(gy), z0f = floorf(gz);
    float fx = gx - x0f, fy = gy - y0f, fz = gz - z0f;
    int x0 = (int)x0f, y0 = (int)y0f, z0 = (int)z0f;
    int x1 = min(x0 + 1, 63), y1 = min(y0 + 1, 63), z1 = min(z0 + 1, 63);

    float w000 = (1.0f-fz)*(1.0f-fy)*(1.0f-fx);
    float w001 = (1.0f-fz)*(1.0f-fy)*fx;
    float w010 = (1.0f-fz)*fy*(1.0f-fx);
    float w011 = (1.0f-fz)*fy*fx;
    float w100 = fz*(1.0f-fy)*(1.0f-fx);
    float w101 = fz*(1.0f-fy)*fx;
    float w110 = fz*fy*(1.0f-fx);
    float w111 = fz*fy*fx;

    float acc0 = 0.f, acc1 = 0.f, acc2 = 0.f, acc3 = 0.f, acc4 = 0.f, acc5 = 0.f;
#define CORNER(zz_, yy_, xx_, ww_)                                              \
    {                                                                           \
        int b = ((((zz_) << 6) | (yy_)) << 6 | (xx_))*3;                        \
        float2 a = v2[b], bb = v2[b+1], cc = v2[b+2];                           \
        acc0 += (ww_)*a.x;  acc1 += (ww_)*a.y;                                  \
        acc2 += (ww_)*bb.x; acc3 += (ww_)*bb.y;                                 \
        acc4 += (ww_)*cc.x; acc5 += (ww_)*cc.y;                                 \
    }
    CORNER(z0, y0, x0, w000)
    CORNER(z0, y0, x1, w001)
    CORNER(z0, y1, x0, w010)
    CORNER(z0, y1, x1, w011)
    CORNER(z1, y0, x0, w100)
    CORNER(z1, y0, x1, w101)
    CORNER(z1, y1, x0, w110)
    CORNER(z1, y1, x1, w111)
#undef CORNER

    float interp[6] = {acc0, acc1, acc2, acc3, acc4, acc5};
    float R2[9], t2v[3];
    se3_exp_dev(interp, R2, t2v);

    float Rn[9], tn[3];
    Rn[0] = R2[0]*Rm[0] + R2[1]*Rm[3] + R2[2]*Rm[6];
    Rn[1] = R2[0]*Rm[1] + R2[1]*Rm[4] + R2[2]*Rm[7];
    Rn[2] = R2[0]*Rm[2] + R2[1]*Rm[5] + R2[2]*Rm[8];
    Rn[3] = R2[3]*Rm[0] + R2[4]*Rm[3] + R2[5]*Rm[6];
    Rn[4] = R2[3]*Rm[1] + R2[4]*Rm[4] + R2[5]*Rm[7];
    Rn[5] = R2[3]*Rm[2] + R2[4]*Rm[5] + R2[5]*Rm[8];
    Rn[6] = R2[6]*Rm[0] + R2[7]*Rm[3] + R2[8]*Rm[6];
    Rn[7] = R2[6]*Rm[1] + R2[7]*Rm[4] + R2[8]*Rm[7];
    Rn[8] = R2[6]*Rm[2] + R2[7]*Rm[5] + R2[8]*Rm[8];
    tn[0] = R2[0]*tm[0] + R2[1]*tm[1] + R2[2]*tm[2] + t2v[0];
    tn[1] = R2[3]*tm[0] + R2[4]*tm[1] + R2[5]*tm[2] + t2v[1];
    tn[2] = R2[6]*tm[0] + R2[7]*tm[1] + R2[8]*tm[2] + t2v[2];

    se3_log_dev(Rn, tn, out6);
}

// ---------- fallback path: init + 7 step dispatches ----------
__global__ __launch_bounds__(256) void init_kernel(const float* __restrict__ in,
                                                   float* __restrict__ vec) {
    int n = blockIdx.x*256 + threadIdx.x;
    const float scale = 1.0f/128.0f;
    float xi[6];
#pragma unroll
    for (int c = 0; c < 6; ++c) xi[c] = in[c*NVOX + n]*scale;
    float2* vp = reinterpret_cast<float2*>(vec + (size_t)n*6);
    vp[0] = make_float2(xi[0], xi[1]);
    vp[1] = make_float2(xi[2], xi[3]);
    vp[2] = make_float2(xi[4], xi[5]);
}

__global__ __launch_bounds__(256) void step_kernel(const float* __restrict__ vin,
                                                   float* __restrict__ vout) {
    int n = blockIdx.x*256 + threadIdx.x;
    const float2* v2 = reinterpret_cast<const float2*>(vin);
    float2 o0 = v2[n*3], o1 = v2[n*3+1], o2 = v2[n*3+2];
    float xi_own[6] = {o0.x, o0.y, o1.x, o1.y, o2.x, o2.y};
    float out6[6];
    step_voxel(n, xi_own, v2, out6);
    float2* op = reinterpret_cast<float2*>(vout + (size_t)n*6);
    op[0] = make_float2(out6[0], out6[1]);
    op[1] = make_float2(out6[2], out6[3]);
    op[2] = make_float2(out6[4], out6[5]);
}

// ---------- fused cooperative: init + 7 steps, field value register-carried ----------
__global__ __launch_bounds__(256, 2)
void fused_kernel(const float* __restrict__ in, float* __restrict__ outbuf,
                  float* __restrict__ bufA) {
    cg::grid_group grid = cg::this_grid();
    const int t = blockIdx.x*256 + threadIdx.x;     // 0 .. NVOX/VPT-1

    const float scale = 1.0f/128.0f;
    float xi[VPT][6];
#pragma unroll
    for (int v = 0; v < VPT; ++v) {
        int n = t + v*(NVOX/VPT);
#pragma unroll
        for (int c = 0; c < 6; ++c) xi[v][c] = in[c*NVOX + n]*scale;
        float2* vp = reinterpret_cast<float2*>(bufA + (size_t)n*6);
        vp[0] = make_float2(xi[v][0], xi[v][1]);
        vp[1] = make_float2(xi[v][2], xi[v][3]);
        vp[2] = make_float2(xi[v][4], xi[v][5]);
    }

    for (int s = 1; s <= NSTEP; ++s) {
        __threadfence();
        grid.sync();
        __threadfence();

        const float* vin  = (s & 1) ? bufA   : outbuf;
        float*       vout = (s & 1) ? outbuf : bufA;
        const float2* v2  = reinterpret_cast<const float2*>(vin);

#pragma unroll
        for (int v = 0; v < VPT; ++v) {
            int n = t + v*(NVOX/VPT);
            float out6[6];
            step_voxel(n, xi[v], v2, out6);
#pragma unroll
            for (int c = 0; c < 6; ++c) xi[v][c] = out6[c];
            float2* op = reinterpret_cast<float2*>(vout + (size_t)n*6);
            op[0] = make_float2(out6[0], out6[1]);
            op[1] = make_float2(out6[2], out6[3]);
            op[2] = make_float2(out6[4], out6[5]);
        }
    }
    // NSTEP=7 odd -> final field in outbuf (d_out)
}

extern "C" void kernel_launch(void* const* d_in, const int* in_sizes, int n_in,
                              void* d_out, int out_size, void* d_ws, size_t ws_size,
                              hipStream_t stream) {
    (void)in_sizes; (void)n_in; (void)out_size; (void)ws_size;
    const float* in = (const float*)d_in[0];
    float* out  = (float*)d_out;
    float* vecA = (float*)d_ws;   // 6 MB ping buffer

    void* args[] = {(void*)&in, (void*)&out, (void*)&vecA};
    hipError_t e = hipLaunchCooperativeKernel((void*)fused_kernel, dim3(FGRID), dim3(256),
                                              args, 0, stream);
    if (e != hipSuccess) {
        // deterministic fallback: proven 8-dispatch path (same math)
        dim3 blk(256), grid(NVOX/256);
        init_kernel<<<grid, blk, 0, stream>>>(in, vecA);
        const float* cur = vecA;
        for (int s = 1; s <= NSTEP; ++s) {
            float* dst = (s & 1) ? out : vecA;
            step_kernel<<<grid, blk, 0, stream>>>(cur, dst);
            cur = dst;
        }
    }
}

// Round 6
// 82.074 us; speedup vs baseline: 14.1010x; 14.1010x over previous
//
#include <hip/hip_runtime.h>
#include <math.h>

#define DSZ   64
#define NVOX  (DSZ*DSZ*DSZ)
#define NSTEP 7
#define SCALE (1.0f/128.0f)   // 1/2^NSTEP

__device__ __forceinline__ float rcp_f(float x)  { return __builtin_amdgcn_rcpf(x); }
__device__ __forceinline__ float rsq_f(float x)  { return __builtin_amdgcn_rsqf(x); }

// ---------- SE(3) exp: xi=(v,w) -> R(3x3 row-major), t(3) ----------
__device__ __forceinline__ void se3_exp_dev(const float xi[6], float R[9], float t[3]) {
    float vx = xi[0], vy = xi[1], vz = xi[2];
    float wx = xi[3], wy = xi[4], wz = xi[5];
    float t2 = wx*wx + wy*wy + wz*wz;
    float t2c = fmaxf(t2, 1e-20f);
    float it    = rsq_f(t2c);        // 1/theta
    float theta = t2c*it;            // theta
    float s = __sinf(theta), c = __cosf(theta);
    float it2 = it*it;
    float A = s*it;
    float B = (1.0f - c)*it2;
    float C = (theta - s)*it2*it;
    bool sm = t2 < 1e-6f;            // error in A/B/C is *theta^2 downstream
    A = sm ? 1.0f - t2*(1.0f/6.0f)            : A;
    B = sm ? 0.5f - t2*(1.0f/24.0f)           : B;
    C = sm ? (1.0f/6.0f) - t2*(1.0f/120.0f)   : C;

    float xx = wx*wx, yy = wy*wy, zz = wz*wz;
    float xy = wx*wy, xz = wx*wz, yz = wy*wz;
    R[0] = 1.0f - B*(yy+zz);
    R[1] = -A*wz + B*xy;
    R[2] =  A*wy + B*xz;
    R[3] =  A*wz + B*xy;
    R[4] = 1.0f - B*(xx+zz);
    R[5] = -A*wx + B*yz;
    R[6] = -A*wy + B*xz;
    R[7] =  A*wx + B*yz;
    R[8] = 1.0f - B*(xx+yy);
    float V0 = 1.0f - C*(yy+zz);
    float V1 = -B*wz + C*xy;
    float V2 =  B*wy + C*xz;
    float V3 =  B*wz + C*xy;
    float V4 = 1.0f - C*(xx+zz);
    float V5 = -B*wx + C*yz;
    float V6 = -B*wy + C*xz;
    float V7 =  B*wx + C*yz;
    float V8 = 1.0f - C*(xx+yy);
    t[0] = V0*vx + V1*vy + V2*vz;
    t[1] = V3*vx + V4*vy + V5*vz;
    t[2] = V6*vx + V7*vy + V8*vz;
}

// ---------- SE(3) log: R,t -> xi=(v,w); sin recovered from cos ----------
__device__ __forceinline__ void se3_log_dev(const float R[9], const float t[3], float out[6]) {
    float tr = R[0] + R[4] + R[8];
    float cs = (tr - 1.0f)*0.5f;
    cs = fminf(fmaxf(cs, -1.0f + 1e-6f), 1.0f - 1e-6f);
    float theta = acosf(cs);
    float t2 = theta*theta;
    float ss2 = 1.0f - cs*cs;          // sin^2
    float isn = rsq_f(ss2);            // 1/sin
    float fac = theta*isn;             // theta/sin
    float sn  = ss2*isn;               // sin
    float coef = (1.0f - 0.5f*sn*theta*rcp_f(1.0f - cs)) * rcp_f(t2);
    bool sm = theta < 1e-3f;
    fac  = sm ? 1.0f + t2*(1.0f/6.0f) : fac;
    coef = sm ? (1.0f/12.0f)          : coef;

    float wx = 0.5f*(R[7]-R[5])*fac;
    float wy = 0.5f*(R[2]-R[6])*fac;
    float wz = 0.5f*(R[3]-R[1])*fac;
    float xx = wx*wx, yy = wy*wy, zz = wz*wz;
    float xy = wx*wy, xz = wx*wz, yz = wy*wz;
    float V0 = 1.0f - coef*(yy+zz);
    float V1 =  0.5f*wz + coef*xy;
    float V2 = -0.5f*wy + coef*xz;
    float V3 = -0.5f*wz + coef*xy;
    float V4 = 1.0f - coef*(xx+zz);
    float V5 =  0.5f*wx + coef*yz;
    float V6 =  0.5f*wy + coef*xz;
    float V7 = -0.5f*wx + coef*yz;
    float V8 = 1.0f - coef*(xx+yy);
    out[0] = V0*t[0] + V1*t[1] + V2*t[2];
    out[1] = V3*t[0] + V4*t[1] + V5*t[2];
    out[2] = V6*t[0] + V7*t[1] + V8*t[2];
    out[3] = wx; out[4] = wy; out[5] = wz;
}

// MODE 0: first step  — vin = raw input, (6,N) strided, *SCALE; vout padded (N,8)
// MODE 1: middle step — vin padded (N,8); vout padded (N,8)
// MODE 2: last step   — vin padded (N,8); vout compact (N,6) = d_out
template<int MODE>
__global__ __launch_bounds__(256) void step_kernel(const float* __restrict__ vin,
                                                   float* __restrict__ vout) {
    int n = blockIdx.x*256 + threadIdx.x;

    // ---- own field value (exp o log == id -> rebuild matrix from own xi) ----
    float xi_own[6];
    if constexpr (MODE == 0) {
#pragma unroll
        for (int c = 0; c < 6; ++c) xi_own[c] = vin[c*NVOX + n]*SCALE;
    } else {
        const float4* v4 = reinterpret_cast<const float4*>(vin);
        float4 a = v4[n*2], b = v4[n*2+1];
        xi_own[0]=a.x; xi_own[1]=a.y; xi_own[2]=a.z;
        xi_own[3]=a.w; xi_own[4]=b.x; xi_own[5]=b.y;
    }

    float Rm[9], tm[3];
    se3_exp_dev(xi_own, Rm, tm);

    // fixed grid point: n = i*4096 + j*64 + k, ax = (2*idx-63)/63
    int k = n & 63, j = (n >> 6) & 63, i = n >> 12;
    const float inv63 = 1.0f/63.0f;
    float p0 = (float)(2*i - 63)*inv63;
    float p1 = (float)(2*j - 63)*inv63;
    float p2 = (float)(2*k - 63)*inv63;

    // new_loc = R @ p + t
    float nl0 = Rm[0]*p0 + Rm[1]*p1 + Rm[2]*p2 + tm[0];
    float nl1 = Rm[3]*p0 + Rm[4]*p1 + Rm[5]*p2 + tm[1];
    float nl2 = Rm[6]*p0 + Rm[7]*p1 + Rm[8]*p2 + tm[2];

    // samp reversed: x<-nl2, y<-nl1, z<-nl0
    float gx = fminf(fmaxf((nl2 + 1.0f)*0.5f*63.0f, 0.0f), 63.0f);
    float gy = fminf(fmaxf((nl1 + 1.0f)*0.5f*63.0f, 0.0f), 63.0f);
    float gz = fminf(fmaxf((nl0 + 1.0f)*0.5f*63.0f, 0.0f), 63.0f);
    float x0f = floorf(gx), y0f = floorf(gy), z0f = floorf(gz);
    float fx = gx - x0f, fy = gy - y0f, fz = gz - z0f;
    int x0 = (int)x0f, y0 = (int)y0f, z0 = (int)z0f;
    int x1 = min(x0 + 1, 63), y1 = min(y0 + 1, 63), z1 = min(z0 + 1, 63);

    float w000 = (1.0f-fz)*(1.0f-fy)*(1.0f-fx);
    float w001 = (1.0f-fz)*(1.0f-fy)*fx;
    float w010 = (1.0f-fz)*fy*(1.0f-fx);
    float w011 = (1.0f-fz)*fy*fx;
    float w100 = fz*(1.0f-fy)*(1.0f-fx);
    float w101 = fz*(1.0f-fy)*fx;
    float w110 = fz*fy*(1.0f-fx);
    float w111 = fz*fy*fx;

    float acc0 = 0.f, acc1 = 0.f, acc2 = 0.f, acc3 = 0.f, acc4 = 0.f, acc5 = 0.f;
    if constexpr (MODE == 0) {
#define CORNER0(zz_, yy_, xx_, ww_)                                             \
        {                                                                       \
            int b = (((zz_) << 6) | (yy_)) << 6 | (xx_);                        \
            acc0 += (ww_)*vin[b];             acc1 += (ww_)*vin[NVOX + b];      \
            acc2 += (ww_)*vin[2*NVOX + b];    acc3 += (ww_)*vin[3*NVOX + b];    \
            acc4 += (ww_)*vin[4*NVOX + b];    acc5 += (ww_)*vin[5*NVOX + b];    \
        }
        CORNER0(z0, y0, x0, w000)
        CORNER0(z0, y0, x1, w001)
        CORNER0(z0, y1, x0, w010)
        CORNER0(z0, y1, x1, w011)
        CORNER0(z1, y0, x0, w100)
        CORNER0(z1, y0, x1, w101)
        CORNER0(z1, y1, x0, w110)
        CORNER0(z1, y1, x1, w111)
#undef CORNER0
        acc0 *= SCALE; acc1 *= SCALE; acc2 *= SCALE;
        acc3 *= SCALE; acc4 *= SCALE; acc5 *= SCALE;
    } else {
        const float4* v4 = reinterpret_cast<const float4*>(vin);
#define CORNER(zz_, yy_, xx_, ww_)                                              \
        {                                                                       \
            int b = ((((zz_) << 6) | (yy_)) << 6 | (xx_))*2;                    \
            float4 a = v4[b], bb = v4[b+1];                                     \
            acc0 += (ww_)*a.x;  acc1 += (ww_)*a.y;                              \
            acc2 += (ww_)*a.z;  acc3 += (ww_)*a.w;                              \
            acc4 += (ww_)*bb.x; acc5 += (ww_)*bb.y;                             \
        }
        CORNER(z0, y0, x0, w000)
        CORNER(z0, y0, x1, w001)
        CORNER(z0, y1, x0, w010)
        CORNER(z0, y1, x1, w011)
        CORNER(z1, y0, x0, w100)
        CORNER(z1, y0, x1, w101)
        CORNER(z1, y1, x0, w110)
        CORNER(z1, y1, x1, w111)
#undef CORNER
    }

    float interp[6] = {acc0, acc1, acc2, acc3, acc4, acc5};
    float R2[9], t2v[3];
    se3_exp_dev(interp, R2, t2v);

    // compose: Mn = [R2|t2] * [Rm|tm]
    float Rn[9], tn[3];
    Rn[0] = R2[0]*Rm[0] + R2[1]*Rm[3] + R2[2]*Rm[6];
    Rn[1] = R2[0]*Rm[1] + R2[1]*Rm[4] + R2[2]*Rm[7];
    Rn[2] = R2[0]*Rm[2] + R2[1]*Rm[5] + R2[2]*Rm[8];
    Rn[3] = R2[3]*Rm[0] + R2[4]*Rm[3] + R2[5]*Rm[6];
    Rn[4] = R2[3]*Rm[1] + R2[4]*Rm[4] + R2[5]*Rm[7];
    Rn[5] = R2[3]*Rm[2] + R2[4]*Rm[5] + R2[5]*Rm[8];
    Rn[6] = R2[6]*Rm[0] + R2[7]*Rm[3] + R2[8]*Rm[6];
    Rn[7] = R2[6]*Rm[1] + R2[7]*Rm[4] + R2[8]*Rm[7];
    Rn[8] = R2[6]*Rm[2] + R2[7]*Rm[5] + R2[8]*Rm[8];
    tn[0] = R2[0]*tm[0] + R2[1]*tm[1] + R2[2]*tm[2] + t2v[0];
    tn[1] = R2[3]*tm[0] + R2[4]*tm[1] + R2[5]*tm[2] + t2v[1];
    tn[2] = R2[6]*tm[0] + R2[7]*tm[1] + R2[8]*tm[2] + t2v[2];

    float out6[6];
    se3_log_dev(Rn, tn, out6);

    if constexpr (MODE == 2) {
        float2* op = reinterpret_cast<float2*>(vout + (size_t)n*6);
        op[0] = make_float2(out6[0], out6[1]);
        op[1] = make_float2(out6[2], out6[3]);
        op[2] = make_float2(out6[4], out6[5]);
    } else {
        float4* op = reinterpret_cast<float4*>(vout) + (size_t)n*2;
        op[0] = make_float4(out6[0], out6[1], out6[2], out6[3]);
        op[1] = make_float4(out6[4], out6[5], 0.0f, 0.0f);
    }
}

extern "C" void kernel_launch(void* const* d_in, const int* in_sizes, int n_in,
                              void* d_out, int out_size, void* d_ws, size_t ws_size,
                              hipStream_t stream) {
    (void)in_sizes; (void)n_in; (void)out_size; (void)ws_size;
    const float* in = (const float*)d_in[0];
    float* out = (float*)d_out;
    char*  ws  = (char*)d_ws;
    float* bufP0 = (float*)ws;                                  // (N,8) padded, 8 MB
    float* bufP1 = (float*)(ws + (size_t)NVOX*8*sizeof(float)); // (N,8) padded, 8 MB

    dim3 blk(256), grid(NVOX/256);
    // step 1: raw input -> padded P0   (init folded in)
    step_kernel<0><<<grid, blk, 0, stream>>>(in, bufP0);
    // steps 2..6: padded ping-pong
    step_kernel<1><<<grid, blk, 0, stream>>>(bufP0, bufP1);   // s=2
    step_kernel<1><<<grid, blk, 0, stream>>>(bufP1, bufP0);   // s=3
    step_kernel<1><<<grid, blk, 0, stream>>>(bufP0, bufP1);   // s=4
    step_kernel<1><<<grid, blk, 0, stream>>>(bufP1, bufP0);   // s=5
    step_kernel<1><<<grid, blk, 0, stream>>>(bufP0, bufP1);   // s=6
    // step 7: padded -> compact d_out
    step_kernel<2><<<grid, blk, 0, stream>>>(bufP1, out);
}

// Round 7
// 73.726 us; speedup vs baseline: 15.6975x; 1.1132x over previous
//
#include <hip/hip_runtime.h>
#include <math.h>

#define DSZ   64
#define NVOX  (DSZ*DSZ*DSZ)
#define NSTEP 7
#define SCALE (1.0f/128.0f)   // 1/2^NSTEP

__device__ __forceinline__ float rcp_f(float x)  { return __builtin_amdgcn_rcpf(x); }
__device__ __forceinline__ float rsq_f(float x)  { return __builtin_amdgcn_rsqf(x); }

// ---------- SE(3) exp: xi=(v,w) -> R(3x3 row-major), t(3) ----------
__device__ __forceinline__ void se3_exp_dev(const float xi[6], float R[9], float t[3]) {
    float vx = xi[0], vy = xi[1], vz = xi[2];
    float wx = xi[3], wy = xi[4], wz = xi[5];
    float t2 = wx*wx + wy*wy + wz*wz;
    float t2c = fmaxf(t2, 1e-20f);
    float it    = rsq_f(t2c);        // 1/theta
    float theta = t2c*it;            // theta
    float s = __sinf(theta), c = __cosf(theta);
    float it2 = it*it;
    float A = s*it;
    float B = (1.0f - c)*it2;
    float C = (theta - s)*it2*it;
    bool sm = t2 < 1e-6f;            // error in A/B/C is *theta^2 downstream
    A = sm ? 1.0f - t2*(1.0f/6.0f)            : A;
    B = sm ? 0.5f - t2*(1.0f/24.0f)           : B;
    C = sm ? (1.0f/6.0f) - t2*(1.0f/120.0f)   : C;

    float xx = wx*wx, yy = wy*wy, zz = wz*wz;
    float xy = wx*wy, xz = wx*wz, yz = wy*wz;
    R[0] = 1.0f - B*(yy+zz);
    R[1] = -A*wz + B*xy;
    R[2] =  A*wy + B*xz;
    R[3] =  A*wz + B*xy;
    R[4] = 1.0f - B*(xx+zz);
    R[5] = -A*wx + B*yz;
    R[6] = -A*wy + B*xz;
    R[7] =  A*wx + B*yz;
    R[8] = 1.0f - B*(xx+yy);
    float V0 = 1.0f - C*(yy+zz);
    float V1 = -B*wz + C*xy;
    float V2 =  B*wy + C*xz;
    float V3 =  B*wz + C*xy;
    float V4 = 1.0f - C*(xx+zz);
    float V5 = -B*wx + C*yz;
    float V6 = -B*wy + C*xz;
    float V7 =  B*wx + C*yz;
    float V8 = 1.0f - C*(xx+yy);
    t[0] = V0*vx + V1*vy + V2*vz;
    t[1] = V3*vx + V4*vy + V5*vz;
    t[2] = V6*vx + V7*vy + V8*vz;
}

// ---------- SE(3) log: R,t -> xi=(v,w); sin recovered from cos ----------
__device__ __forceinline__ void se3_log_dev(const float R[9], const float t[3], float out[6]) {
    float tr = R[0] + R[4] + R[8];
    float cs = (tr - 1.0f)*0.5f;
    cs = fminf(fmaxf(cs, -1.0f + 1e-6f), 1.0f - 1e-6f);
    float theta = acosf(cs);
    float t2 = theta*theta;
    float ss2 = 1.0f - cs*cs;          // sin^2
    float isn = rsq_f(ss2);            // 1/sin
    float fac = theta*isn;             // theta/sin
    float sn  = ss2*isn;               // sin
    float coef = (1.0f - 0.5f*sn*theta*rcp_f(1.0f - cs)) * rcp_f(t2);
    bool sm = theta < 1e-3f;
    fac  = sm ? 1.0f + t2*(1.0f/6.0f) : fac;
    coef = sm ? (1.0f/12.0f)          : coef;

    float wx = 0.5f*(R[7]-R[5])*fac;
    float wy = 0.5f*(R[2]-R[6])*fac;
    float wz = 0.5f*(R[3]-R[1])*fac;
    float xx = wx*wx, yy = wy*wy, zz = wz*wz;
    float xy = wx*wy, xz = wx*wz, yz = wy*wz;
    float V0 = 1.0f - coef*(yy+zz);
    float V1 =  0.5f*wz + coef*xy;
    float V2 = -0.5f*wy + coef*xz;
    float V3 = -0.5f*wz + coef*xy;
    float V4 = 1.0f - coef*(xx+zz);
    float V5 =  0.5f*wx + coef*yz;
    float V6 =  0.5f*wy + coef*xz;
    float V7 = -0.5f*wx + coef*yz;
    float V8 = 1.0f - coef*(xx+yy);
    out[0] = V0*t[0] + V1*t[1] + V2*t[2];
    out[1] = V3*t[0] + V4*t[1] + V5*t[2];
    out[2] = V6*t[0] + V7*t[1] + V8*t[2];
    out[3] = wx; out[4] = wy; out[5] = wz;
}

// MODE 0: first step — vin = raw input, (6,N) strided, scale folded in; vout (N,6)
// MODE 1: other steps — vin (N,6) float2; vout (N,6)   (d_out has same layout)
template<int MODE>
__global__ __launch_bounds__(256) void step_kernel(const float* __restrict__ vin,
                                                   float* __restrict__ vout) {
    int n = blockIdx.x*256 + threadIdx.x;

    // ---- own field value (exp o log == id -> rebuild matrix from own xi) ----
    float xi_own[6];
    if constexpr (MODE == 0) {
#pragma unroll
        for (int c = 0; c < 6; ++c) xi_own[c] = vin[c*NVOX + n]*SCALE;
    } else {
        const float2* v2 = reinterpret_cast<const float2*>(vin);
        float2 a = v2[n*3], b = v2[n*3+1], cgl = v2[n*3+2];
        xi_own[0]=a.x; xi_own[1]=a.y; xi_own[2]=b.x;
        xi_own[3]=b.y; xi_own[4]=cgl.x; xi_own[5]=cgl.y;
    }

    float Rm[9], tm[3];
    se3_exp_dev(xi_own, Rm, tm);

    // fixed grid point: n = i*4096 + j*64 + k, ax = (2*idx-63)/63
    int k = n & 63, j = (n >> 6) & 63, i = n >> 12;
    const float inv63 = 1.0f/63.0f;
    float p0 = (float)(2*i - 63)*inv63;
    float p1 = (float)(2*j - 63)*inv63;
    float p2 = (float)(2*k - 63)*inv63;

    // new_loc = R @ p + t
    float nl0 = Rm[0]*p0 + Rm[1]*p1 + Rm[2]*p2 + tm[0];
    float nl1 = Rm[3]*p0 + Rm[4]*p1 + Rm[5]*p2 + tm[1];
    float nl2 = Rm[6]*p0 + Rm[7]*p1 + Rm[8]*p2 + tm[2];

    // samp reversed: x<-nl2, y<-nl1, z<-nl0
    float gx = fminf(fmaxf((nl2 + 1.0f)*0.5f*63.0f, 0.0f), 63.0f);
    float gy = fminf(fmaxf((nl1 + 1.0f)*0.5f*63.0f, 0.0f), 63.0f);
    float gz = fminf(fmaxf((nl0 + 1.0f)*0.5f*63.0f, 0.0f), 63.0f);
    float x0f = floorf(gx), y0f = floorf(gy), z0f = floorf(gz);
    float fx = gx - x0f, fy = gy - y0f, fz = gz - z0f;
    int x0 = (int)x0f, y0 = (int)y0f, z0 = (int)z0f;
    int x1 = min(x0 + 1, 63), y1 = min(y0 + 1, 63), z1 = min(z0 + 1, 63);

    float w000 = (1.0f-fz)*(1.0f-fy)*(1.0f-fx);
    float w001 = (1.0f-fz)*(1.0f-fy)*fx;
    float w010 = (1.0f-fz)*fy*(1.0f-fx);
    float w011 = (1.0f-fz)*fy*fx;
    float w100 = fz*(1.0f-fy)*(1.0f-fx);
    float w101 = fz*(1.0f-fy)*fx;
    float w110 = fz*fy*(1.0f-fx);
    float w111 = fz*fy*fx;

    float acc0 = 0.f, acc1 = 0.f, acc2 = 0.f, acc3 = 0.f, acc4 = 0.f, acc5 = 0.f;
    if constexpr (MODE == 0) {
#define CORNER0(zz_, yy_, xx_, ww_)                                             \
        {                                                                       \
            int b = (((zz_) << 6) | (yy_)) << 6 | (xx_);                        \
            acc0 += (ww_)*vin[b];             acc1 += (ww_)*vin[NVOX + b];      \
            acc2 += (ww_)*vin[2*NVOX + b];    acc3 += (ww_)*vin[3*NVOX + b];    \
            acc4 += (ww_)*vin[4*NVOX + b];    acc5 += (ww_)*vin[5*NVOX + b];    \
        }
        CORNER0(z0, y0, x0, w000)
        CORNER0(z0, y0, x1, w001)
        CORNER0(z0, y1, x0, w010)
        CORNER0(z0, y1, x1, w011)
        CORNER0(z1, y0, x0, w100)
        CORNER0(z1, y0, x1, w101)
        CORNER0(z1, y1, x0, w110)
        CORNER0(z1, y1, x1, w111)
#undef CORNER0
        acc0 *= SCALE; acc1 *= SCALE; acc2 *= SCALE;
        acc3 *= SCALE; acc4 *= SCALE; acc5 *= SCALE;
    } else {
        const float2* v2 = reinterpret_cast<const float2*>(vin);
#define CORNER(zz_, yy_, xx_, ww_)                                              \
        {                                                                       \
            int b = ((((zz_) << 6) | (yy_)) << 6 | (xx_))*3;                    \
            float2 a = v2[b], bb = v2[b+1], cc = v2[b+2];                       \
            acc0 += (ww_)*a.x;  acc1 += (ww_)*a.y;                              \
            acc2 += (ww_)*bb.x; acc3 += (ww_)*bb.y;                             \
            acc4 += (ww_)*cc.x; acc5 += (ww_)*cc.y;                             \
        }
        CORNER(z0, y0, x0, w000)
        CORNER(z0, y0, x1, w001)
        CORNER(z0, y1, x0, w010)
        CORNER(z0, y1, x1, w011)
        CORNER(z1, y0, x0, w100)
        CORNER(z1, y0, x1, w101)
        CORNER(z1, y1, x0, w110)
        CORNER(z1, y1, x1, w111)
#undef CORNER
    }

    float interp[6] = {acc0, acc1, acc2, acc3, acc4, acc5};
    float R2[9], t2v[3];
    se3_exp_dev(interp, R2, t2v);

    // compose: Mn = [R2|t2] * [Rm|tm]
    float Rn[9], tn[3];
    Rn[0] = R2[0]*Rm[0] + R2[1]*Rm[3] + R2[2]*Rm[6];
    Rn[1] = R2[0]*Rm[1] + R2[1]*Rm[4] + R2[2]*Rm[7];
    Rn[2] = R2[0]*Rm[2] + R2[1]*Rm[5] + R2[2]*Rm[8];
    Rn[3] = R2[3]*Rm[0] + R2[4]*Rm[3] + R2[5]*Rm[6];
    Rn[4] = R2[3]*Rm[1] + R2[4]*Rm[4] + R2[5]*Rm[7];
    Rn[5] = R2[3]*Rm[2] + R2[4]*Rm[5] + R2[5]*Rm[8];
    Rn[6] = R2[6]*Rm[0] + R2[7]*Rm[3] + R2[8]*Rm[6];
    Rn[7] = R2[6]*Rm[1] + R2[7]*Rm[4] + R2[8]*Rm[7];
    Rn[8] = R2[6]*Rm[2] + R2[7]*Rm[5] + R2[8]*Rm[8];
    tn[0] = R2[0]*tm[0] + R2[1]*tm[1] + R2[2]*tm[2] + t2v[0];
    tn[1] = R2[3]*tm[0] + R2[4]*tm[1] + R2[5]*tm[2] + t2v[1];
    tn[2] = R2[6]*tm[0] + R2[7]*tm[1] + R2[8]*tm[2] + t2v[2];

    float out6[6];
    se3_log_dev(Rn, tn, out6);
    float2* op = reinterpret_cast<float2*>(vout + (size_t)n*6);
    op[0] = make_float2(out6[0], out6[1]);
    op[1] = make_float2(out6[2], out6[3]);
    op[2] = make_float2(out6[4], out6[5]);
}

extern "C" void kernel_launch(void* const* d_in, const int* in_sizes, int n_in,
                              void* d_out, int out_size, void* d_ws, size_t ws_size,
                              hipStream_t stream) {
    (void)in_sizes; (void)n_in; (void)out_size; (void)ws_size;
    const float* in = (const float*)d_in[0];
    float* out = (float*)d_out;
    char*  ws  = (char*)d_ws;
    float* bufA = (float*)ws;                                   // (N,6), 6 MB
    float* bufB = (float*)(ws + (size_t)NVOX*6*sizeof(float));  // (N,6), 6 MB

    dim3 blk(256), grid(NVOX/256);
    // step 1: raw input -> bufA (init folded in)
    step_kernel<0><<<grid, blk, 0, stream>>>(in, bufA);
    // steps 2..6: ping-pong; step 7 -> d_out (same (N,6) layout)
    step_kernel<1><<<grid, blk, 0, stream>>>(bufA, bufB);   // s=2
    step_kernel<1><<<grid, blk, 0, stream>>>(bufB, bufA);   // s=3
    step_kernel<1><<<grid, blk, 0, stream>>>(bufA, bufB);   // s=4
    step_kernel<1><<<grid, blk, 0, stream>>>(bufB, bufA);   // s=5
    step_kernel<1><<<grid, blk, 0, stream>>>(bufA, bufB);   // s=6
    step_kernel<1><<<grid, blk, 0, stream>>>(bufB, out);    // s=7
}

// Round 8
// 64.226 us; speedup vs baseline: 18.0195x; 1.1479x over previous
//
#include <hip/hip_runtime.h>
#include <math.h>

#define DSZ   64
#define NVOX  (DSZ*DSZ*DSZ)
#define NSTEP 7
#define SCALE (1.0f/128.0f)   // 1/2^NSTEP

__device__ __forceinline__ float rcp_f(float x)  { return __builtin_amdgcn_rcpf(x); }
__device__ __forceinline__ float rsq_f(float x)  { return __builtin_amdgcn_rsqf(x); }

// Abramowitz-Stegun 4.4.45: |err| <= 6.8e-5 rad over [-1,1]
__device__ __forceinline__ float acos_fast(float x) {
    float ax = fabsf(x);
    float p = ((-0.0187293f*ax + 0.0742610f)*ax - 0.2121144f)*ax + 1.5707288f;
    float r = sqrtf(1.0f - ax) * p;
    return (x >= 0.0f) ? r : 3.14159265358979f - r;
}

// ---------- SE(3) exp: xi=(v,w) -> R(3x3 row-major), t(3) ----------
__device__ __forceinline__ void se3_exp_dev(const float xi[6], float R[9], float t[3]) {
    float vx = xi[0], vy = xi[1], vz = xi[2];
    float wx = xi[3], wy = xi[4], wz = xi[5];
    float t2 = wx*wx + wy*wy + wz*wz;
    float t2c = fmaxf(t2, 1e-20f);
    float it    = rsq_f(t2c);        // 1/theta
    float theta = t2c*it;            // theta
    float s = __sinf(theta), c = __cosf(theta);
    float it2 = it*it;
    float A = s*it;
    float B = (1.0f - c)*it2;
    float C = (theta - s)*it2*it;
    bool sm = t2 < 1e-6f;            // error in A/B/C is *theta^2 downstream
    A = sm ? 1.0f - t2*(1.0f/6.0f)            : A;
    B = sm ? 0.5f - t2*(1.0f/24.0f)           : B;
    C = sm ? (1.0f/6.0f) - t2*(1.0f/120.0f)   : C;

    float xx = wx*wx, yy = wy*wy, zz = wz*wz;
    float xy = wx*wy, xz = wx*wz, yz = wy*wz;
    R[0] = 1.0f - B*(yy+zz);
    R[1] = -A*wz + B*xy;
    R[2] =  A*wy + B*xz;
    R[3] =  A*wz + B*xy;
    R[4] = 1.0f - B*(xx+zz);
    R[5] = -A*wx + B*yz;
    R[6] = -A*wy + B*xz;
    R[7] =  A*wx + B*yz;
    R[8] = 1.0f - B*(xx+yy);
    float V0 = 1.0f - C*(yy+zz);
    float V1 = -B*wz + C*xy;
    float V2 =  B*wy + C*xz;
    float V3 =  B*wz + C*xy;
    float V4 = 1.0f - C*(xx+zz);
    float V5 = -B*wx + C*yz;
    float V6 = -B*wy + C*xz;
    float V7 =  B*wx + C*yz;
    float V8 = 1.0f - C*(xx+yy);
    t[0] = V0*vx + V1*vy + V2*vz;
    t[1] = V3*vx + V4*vy + V5*vz;
    t[2] = V6*vx + V7*vy + V8*vz;
}

// ---------- SE(3) log: R,t -> xi=(v,w); sin recovered from cos ----------
__device__ __forceinline__ void se3_log_dev(const float R[9], const float t[3], float out[6]) {
    float tr = R[0] + R[4] + R[8];
    float cs = (tr - 1.0f)*0.5f;
    cs = fminf(fmaxf(cs, -1.0f + 1e-6f), 1.0f - 1e-6f);
    float theta = acos_fast(cs);
    float t2 = theta*theta;
    float ss2 = 1.0f - cs*cs;          // sin^2
    float isn = rsq_f(ss2);            // 1/sin
    float fac = theta*isn;             // theta/sin
    float sn  = ss2*isn;               // sin
    float coef = (1.0f - 0.5f*sn*theta*rcp_f(1.0f - cs)) * rcp_f(t2);
    bool sm = theta < 1e-3f;
    fac  = sm ? 1.0f + t2*(1.0f/6.0f) : fac;
    coef = sm ? (1.0f/12.0f)          : coef;

    float wx = 0.5f*(R[7]-R[5])*fac;
    float wy = 0.5f*(R[2]-R[6])*fac;
    float wz = 0.5f*(R[3]-R[1])*fac;
    float xx = wx*wx, yy = wy*wy, zz = wz*wz;
    float xy = wx*wy, xz = wx*wz, yz = wy*wz;
    float V0 = 1.0f - coef*(yy+zz);
    float V1 =  0.5f*wz + coef*xy;
    float V2 = -0.5f*wy + coef*xz;
    float V3 = -0.5f*wz + coef*xy;
    float V4 = 1.0f - coef*(xx+zz);
    float V5 =  0.5f*wx + coef*yz;
    float V6 =  0.5f*wy + coef*xz;
    float V7 = -0.5f*wx + coef*yz;
    float V8 = 1.0f - coef*(xx+yy);
    out[0] = V0*t[0] + V1*t[1] + V2*t[2];
    out[1] = V3*t[0] + V4*t[1] + V5*t[2];
    out[2] = V6*t[0] + V7*t[1] + V8*t[2];
    out[3] = wx; out[4] = wy; out[5] = wz;
}

// MODE 0: first step — vin = raw input, (6,N) strided, scale folded in; vout (N,6)
// MODE 1: other steps — vin (N,6) float2; vout (N,6)   (d_out has same layout)
template<int MODE>
__global__ __launch_bounds__(256) void step_kernel(const float* __restrict__ vin,
                                                   float* __restrict__ vout) {
    // XCD-aware swizzle: blocks round-robin across 8 XCDs (b&7); give each XCD
    // a contiguous 128-work-block z-slab (8 planes) so gathers hit its own L2.
    int wb = ((blockIdx.x & 7) << 7) | (blockIdx.x >> 3);
    int n = wb*256 + threadIdx.x;

    // ---- own field value (exp o log == id -> rebuild matrix from own xi) ----
    float xi_own[6];
    if constexpr (MODE == 0) {
#pragma unroll
        for (int c = 0; c < 6; ++c) xi_own[c] = vin[c*NVOX + n]*SCALE;
    } else {
        const float2* v2 = reinterpret_cast<const float2*>(vin);
        float2 a = v2[n*3], b = v2[n*3+1], cgl = v2[n*3+2];
        xi_own[0]=a.x; xi_own[1]=a.y; xi_own[2]=b.x;
        xi_own[3]=b.y; xi_own[4]=cgl.x; xi_own[5]=cgl.y;
    }

    float Rm[9], tm[3];
    se3_exp_dev(xi_own, Rm, tm);

    // fixed grid point: n = i*4096 + j*64 + k, ax = (2*idx-63)/63
    int k = n & 63, j = (n >> 6) & 63, i = n >> 12;
    const float inv63 = 1.0f/63.0f;
    float p0 = (float)(2*i - 63)*inv63;
    float p1 = (float)(2*j - 63)*inv63;
    float p2 = (float)(2*k - 63)*inv63;

    // new_loc = R @ p + t
    float nl0 = Rm[0]*p0 + Rm[1]*p1 + Rm[2]*p2 + tm[0];
    float nl1 = Rm[3]*p0 + Rm[4]*p1 + Rm[5]*p2 + tm[1];
    float nl2 = Rm[6]*p0 + Rm[7]*p1 + Rm[8]*p2 + tm[2];

    // samp reversed: x<-nl2, y<-nl1, z<-nl0
    float gx = fminf(fmaxf((nl2 + 1.0f)*0.5f*63.0f, 0.0f), 63.0f);
    float gy = fminf(fmaxf((nl1 + 1.0f)*0.5f*63.0f, 0.0f), 63.0f);
    float gz = fminf(fmaxf((nl0 + 1.0f)*0.5f*63.0f, 0.0f), 63.0f);
    float x0f = floorf(gx), y0f = floorf(gy), z0f = floorf(gz);
    float fx = gx - x0f, fy = gy - y0f, fz = gz - z0f;
    int x0 = (int)x0f, y0 = (int)y0f, z0 = (int)z0f;
    int x1 = min(x0 + 1, 63), y1 = min(y0 + 1, 63), z1 = min(z0 + 1, 63);

    float w000 = (1.0f-fz)*(1.0f-fy)*(1.0f-fx);
    float w001 = (1.0f-fz)*(1.0f-fy)*fx;
    float w010 = (1.0f-fz)*fy*(1.0f-fx);
    float w011 = (1.0f-fz)*fy*fx;
    float w100 = fz*(1.0f-fy)*(1.0f-fx);
    float w101 = fz*(1.0f-fy)*fx;
    float w110 = fz*fy*(1.0f-fx);
    float w111 = fz*fy*fx;

    float acc0 = 0.f, acc1 = 0.f, acc2 = 0.f, acc3 = 0.f, acc4 = 0.f, acc5 = 0.f;
    if constexpr (MODE == 0) {
#define CORNER0(zz_, yy_, xx_, ww_)                                             \
        {                                                                       \
            int b = (((zz_) << 6) | (yy_)) << 6 | (xx_);                        \
            acc0 += (ww_)*vin[b];             acc1 += (ww_)*vin[NVOX + b];      \
            acc2 += (ww_)*vin[2*NVOX + b];    acc3 += (ww_)*vin[3*NVOX + b];    \
            acc4 += (ww_)*vin[4*NVOX + b];    acc5 += (ww_)*vin[5*NVOX + b];    \
        }
        CORNER0(z0, y0, x0, w000)
        CORNER0(z0, y0, x1, w001)
        CORNER0(z0, y1, x0, w010)
        CORNER0(z0, y1, x1, w011)
        CORNER0(z1, y0, x0, w100)
        CORNER0(z1, y0, x1, w101)
        CORNER0(z1, y1, x0, w110)
        CORNER0(z1, y1, x1, w111)
#undef CORNER0
        acc0 *= SCALE; acc1 *= SCALE; acc2 *= SCALE;
        acc3 *= SCALE; acc4 *= SCALE; acc5 *= SCALE;
    } else {
        const float2* v2 = reinterpret_cast<const float2*>(vin);
#define CORNER(zz_, yy_, xx_, ww_)                                              \
        {                                                                       \
            int b = ((((zz_) << 6) | (yy_)) << 6 | (xx_))*3;                    \
            float2 a = v2[b], bb = v2[b+1], cc = v2[b+2];                       \
            acc0 += (ww_)*a.x;  acc1 += (ww_)*a.y;                              \
            acc2 += (ww_)*bb.x; acc3 += (ww_)*bb.y;                             \
            acc4 += (ww_)*cc.x; acc5 += (ww_)*cc.y;                             \
        }
        CORNER(z0, y0, x0, w000)
        CORNER(z0, y0, x1, w001)
        CORNER(z0, y1, x0, w010)
        CORNER(z0, y1, x1, w011)
        CORNER(z1, y0, x0, w100)
        CORNER(z1, y0, x1, w101)
        CORNER(z1, y1, x0, w110)
        CORNER(z1, y1, x1, w111)
#undef CORNER
    }

    float interp[6] = {acc0, acc1, acc2, acc3, acc4, acc5};
    float R2[9], t2v[3];
    se3_exp_dev(interp, R2, t2v);

    // compose: Mn = [R2|t2] * [Rm|tm]
    float Rn[9], tn[3];
    Rn[0] = R2[0]*Rm[0] + R2[1]*Rm[3] + R2[2]*Rm[6];
    Rn[1] = R2[0]*Rm[1] + R2[1]*Rm[4] + R2[2]*Rm[7];
    Rn[2] = R2[0]*Rm[2] + R2[1]*Rm[5] + R2[2]*Rm[8];
    Rn[3] = R2[3]*Rm[0] + R2[4]*Rm[3] + R2[5]*Rm[6];
    Rn[4] = R2[3]*Rm[1] + R2[4]*Rm[4] + R2[5]*Rm[7];
    Rn[5] = R2[3]*Rm[2] + R2[4]*Rm[5] + R2[5]*Rm[8];
    Rn[6] = R2[6]*Rm[0] + R2[7]*Rm[3] + R2[8]*Rm[6];
    Rn[7] = R2[6]*Rm[1] + R2[7]*Rm[4] + R2[8]*Rm[7];
    Rn[8] = R2[6]*Rm[2] + R2[7]*Rm[5] + R2[8]*Rm[8];
    tn[0] = R2[0]*tm[0] + R2[1]*tm[1] + R2[2]*tm[2] + t2v[0];
    tn[1] = R2[3]*tm[0] + R2[4]*tm[1] + R2[5]*tm[2] + t2v[1];
    tn[2] = R2[6]*tm[0] + R2[7]*tm[1] + R2[8]*tm[2] + t2v[2];

    float out6[6];
    se3_log_dev(Rn, tn, out6);
    float2* op = reinterpret_cast<float2*>(vout + (size_t)n*6);
    op[0] = make_float2(out6[0], out6[1]);
    op[1] = make_float2(out6[2], out6[3]);
    op[2] = make_float2(out6[4], out6[5]);
}

extern "C" void kernel_launch(void* const* d_in, const int* in_sizes, int n_in,
                              void* d_out, int out_size, void* d_ws, size_t ws_size,
                              hipStream_t stream) {
    (void)in_sizes; (void)n_in; (void)out_size; (void)ws_size;
    const float* in = (const float*)d_in[0];
    float* out = (float*)d_out;
    char*  ws  = (char*)d_ws;
    float* bufA = (float*)ws;                                   // (N,6), 6 MB
    float* bufB = (float*)(ws + (size_t)NVOX*6*sizeof(float));  // (N,6), 6 MB

    dim3 blk(256), grid(NVOX/256);
    // step 1: raw input -> bufA (init folded in)
    step_kernel<0><<<grid, blk, 0, stream>>>(in, bufA);
    // steps 2..6: ping-pong; step 7 -> d_out (same (N,6) layout)
    step_kernel<1><<<grid, blk, 0, stream>>>(bufA, bufB);   // s=2
    step_kernel<1><<<grid, blk, 0, stream>>>(bufB, bufA);   // s=3
    step_kernel<1><<<grid, blk, 0, stream>>>(bufA, bufB);   // s=4
    step_kernel<1><<<grid, blk, 0, stream>>>(bufB, bufA);   // s=5
    step_kernel<1><<<grid, blk, 0, stream>>>(bufA, bufB);   // s=6
    step_kernel<1><<<grid, blk, 0, stream>>>(bufB, out);    // s=7
}